// Round 7
// baseline (5609.000 us; speedup 1.0000x reference)
//
#include <hip/hip_runtime.h>
#include <stdint.h>

// FPS: B=64, N=32768, C=3, S=1024.
// Round-7 structure: 4 blocks per batch (256 blocks = all 256 CUs), each
// block owns a contiguous 8192-point slice. All three coord planes live in
// LDS (96 KB: float2 xy + float z) -> zero global traffic in the hot loop
// and no regalloc fight (rounds 4-6 showed the allocator refuses >64 VGPRs
// and spills instead). Per-step global argmax = intra-block reduce +
// cross-block combine through device-scope atomics in d_ws:
//   publish: slot[b][part][s%4] = (s<<48) | (val_bits<<16) | (0xFFFF-idx)
//   poll:    lanes 0-3 of wave 0 wait for tag==s, u64-max combines
//            (val_bits monotonic for nonneg floats; ~idx gives min-index ties)
// d_ws tags are cleared by hipMemsetAsync each launch, so graph replays
// never see stale tags (writer can then never lap a lagging reader: passing
// the poll of step s-1 proves all peers finished reading step s-2).
// Co-residency: 96KB LDS forces 1 block/CU; 256 blocks on 256 CUs.
// blockIdx = part*B + b puts a batch's 4 parts on the same XCD (heuristic).
//
// Exactness (bit-exact trajectory vs XLA-CPU reference, validated round 3):
//   d = fma(dz,dz, fma(dx,dx, dy*dy)), fminf running min,
//   first-occurrence argmax (strict >, ascending index; min index on ties).
//   Slices are disjoint; combine preserves min-global-index tie-break.

#define FPS_N   32768
#define FPS_S   1024
#define NPARTS  4
#define PPB     (FPS_N / NPARTS)   // 8192 points per block
#define FPS_NT  512
#define PPT     (PPB / FPS_NT)     // 16 points per thread
#define RING    4

typedef unsigned long long u64;
typedef unsigned int u32;

__device__ __forceinline__ u64 shfl_xor_u64(u64 v, int lanemask) {
    int lo = __shfl_xor((int)(u32)(v & 0xFFFFFFFFull), lanemask);
    int hi = __shfl_xor((int)(u32)(v >> 32), lanemask);
    return ((u64)(u32)hi << 32) | (u32)lo;
}

__global__ __launch_bounds__(FPS_NT) void FPSModel_80753975099708_kernel(
    const float* __restrict__ x,   // [B, N, 3]
    float* __restrict__ out_pts,   // [B, S, 3]
    float* __restrict__ out_idx,   // [B, S] (indices stored as float values)
    u64* __restrict__ slots,       // [B][NPARTS][RING], zeroed per launch
    int B)
{
#pragma clang fp contract(off)
    const int part = blockIdx.x / B;          // parts of batch b: b, B+b, 2B+b, 3B+b
    const int b    = blockIdx.x % B;
    const int t    = threadIdx.x;
    const int base = part * PPB;

    const float* __restrict__ xb = x + (size_t)b * FPS_N * 3;
    float* __restrict__ op = out_pts + (size_t)b * FPS_S * 3;
    float* __restrict__ oi = out_idx + (size_t)b * FPS_S;

    __shared__ float2 xy[PPB];                 // 65536 B
    __shared__ float  zs[PPB];                 // 32768 B
    __shared__ float2 red[2][FPS_NT / 64];     // per-wave (value, idx-bits)
    __shared__ int    bc[2];                   // winner broadcast

    float mind[PPT];

    // Prologue: stage this block's slice into LDS.
#pragma unroll
    for (int j = 0; j < PPT; ++j) {
        const int il = j * FPS_NT + t;
        const float* __restrict__ p = xb + (size_t)(base + il) * 3;
        xy[il] = make_float2(p[0], p[1]);
        zs[il] = p[2];
        mind[j] = __int_as_float(0x7f800000);  // +inf
    }

    int cur = 0;
    if (part == 0 && t == 0) {
        oi[0] = 0.0f;
        op[0] = xb[0];
        op[1] = xb[1];
        op[2] = xb[2];
    }
    __syncthreads();

    for (int s = 1; s < FPS_S; ++s) {
        // Broadcast read of current farthest point (12 B, L2-hot).
        const float px = xb[(size_t)cur * 3 + 0];
        const float py = xb[(size_t)cur * 3 + 1];
        const float pz = xb[(size_t)cur * 3 + 2];

        float bestv = __int_as_float(0xff800000); // -inf
        int   bestj = 0;

#pragma unroll
        for (int j = 0; j < PPT; ++j) {
            const int il = j * FPS_NT + t;
            const float2 cxy = xy[il];
            const float dx = cxy.x - px;
            const float dy = cxy.y - py;
            const float dz = zs[il] - pz;
            // XLA-CPU contracted form: fma(dz,dz, fma(dx,dx, dy*dy))
            const float dyy = dy * dy;
            const float u   = __builtin_fmaf(dx, dx, dyy);
            const float d   = __builtin_fmaf(dz, dz, u);
            const float m = fminf(mind[j], d);
            mind[j] = m;
            if (m > bestv) { bestv = m; bestj = j; }  // ascending j => first occ.
        }
        int besti = bestj * FPS_NT + t;               // local slice index

        // Wave butterfly (64 lanes), tie-break to smaller index.
#pragma unroll
        for (int off = 32; off; off >>= 1) {
            const float ov = __shfl_xor(bestv, off);
            const int   ob = __shfl_xor(besti, off);
            if (ov > bestv || (ov == bestv && ob < besti)) { bestv = ov; besti = ob; }
        }
        if ((t & 63) == 0) {
            red[s & 1][t >> 6] = make_float2(bestv, __int_as_float(besti));
        }
        __syncthreads();

        if (t < 64) {
            // Block-level scan of the 8 wave slots (wave 0 only).
            float gv = __int_as_float(0xff800000);
            int   gi = 0x7fffffff;
#pragma unroll
            for (int w = 0; w < FPS_NT / 64; ++w) {
                const float2 e = red[s & 1][w];
                const int ei = __float_as_int(e.y);
                if (e.x > gv || (e.x == gv && ei < gi)) { gv = e.x; gi = ei; }
            }
            const u32 gidx = (u32)(base + gi);        // 15-bit global index
            const u64 key = ((u64)__float_as_uint(gv) << 16) | (u64)(0xFFFFu - gidx);

            if (t == 0) {
                __hip_atomic_store(
                    &slots[(size_t)(b * NPARTS + part) * RING + (s & (RING - 1))],
                    ((u64)(u32)s << 48) | key,
                    __ATOMIC_RELEASE, __HIP_MEMORY_SCOPE_AGENT);
            }

            u64 cand = 0;
            if (t < NPARTS) {
                if (t == part) {
                    cand = key;
                } else {
                    const u64* sl =
                        &slots[(size_t)(b * NPARTS + t) * RING + (s & (RING - 1))];
                    u64 v;
                    do {
                        v = __hip_atomic_load(sl, __ATOMIC_ACQUIRE,
                                              __HIP_MEMORY_SCOPE_AGENT);
                    } while ((u32)(v >> 48) != (u32)s);
                    cand = v & 0x0000FFFFFFFFFFFFull;
                }
            }
            // Combine the 4 candidates (lanes 0-3); max key = max val, min idx.
            u64 o = shfl_xor_u64(cand, 1); if (o > cand) cand = o;
            o     = shfl_xor_u64(cand, 2); if (o > cand) cand = o;
            if (t == 0) bc[s & 1] = (int)(0xFFFFu - (u32)(cand & 0xFFFFu));
        }
        __syncthreads();
        cur = bc[s & 1];

        if (part == 0 && t == 0) {
            oi[s] = (float)cur;
            const float* __restrict__ p = xb + (size_t)cur * 3;
            op[(size_t)s * 3 + 0] = p[0];
            op[(size_t)s * 3 + 1] = p[1];
            op[(size_t)s * 3 + 2] = p[2];
        }
    }
}

extern "C" void kernel_launch(void* const* d_in, const int* in_sizes, int n_in,
                              void* d_out, int out_size, void* d_ws, size_t ws_size,
                              hipStream_t stream) {
    const float* x = (const float*)d_in[0];
    const int B = in_sizes[0] / (FPS_N * 3);

    float* out_pts = (float*)d_out;
    float* out_idx = out_pts + (size_t)B * FPS_S * 3;
    u64* slots = (u64*)d_ws;

    // Clear sync tags every launch (graph-captured; stream-ordered).
    hipMemsetAsync(d_ws, 0, (size_t)B * NPARTS * RING * sizeof(u64), stream);

    hipLaunchKernelGGL(FPSModel_80753975099708_kernel,
                       dim3(B * NPARTS), dim3(FPS_NT), 0, stream,
                       x, out_pts, out_idx, slots, B);
}